// Round 1
// baseline (8432.425 us; speedup 1.0000x reference)
//
#include <hip/hip_runtime.h>

// Problem constants
#define B_    4096
#define F_    39
#define D_    16
#define L0_   128
#define H1_   64
#define K0_   (F_ * F_)    // 1521
#define K1_   (H1_ * F_)   // 2496
#define OUTB_ 192          // 64 (direct0) + 128 (direct1) per batch element

// ---------------- Layer 0 ----------------
// y0[b,o,d] = relu(b0[o] + sum_{h,m} W0[o, h*39+m] * x[b,h,d]*x[b,m,d])
// o in [0,64)  -> next_hidden (to ws)
// o in [64,128)-> direct0: out[b, o-64] = sum_d y0[b,o,d]
__global__ __launch_bounds__(256) void cin_layer0(
    const float* __restrict__ x, const float* __restrict__ W0,
    const float* __restrict__ b0, float* __restrict__ out,
    float* __restrict__ nh)
{
    __shared__ float xs[F_ * D_];     // 624 floats
    __shared__ float ys[H1_ * D_];    // direct0 staging, 1024 floats

    const int b = blockIdx.x;
    const int t = threadIdx.x;
    const float* xb = x + (size_t)b * (F_ * D_);
    for (int i = t; i < F_ * D_; i += 256) xs[i] = xb[i];
    __syncthreads();

    const int d    = t & 15;
    const int orow = t >> 4;          // 0..15; this thread's o = orow + 16*j

    float acc[8];
#pragma unroll
    for (int j = 0; j < 8; ++j) acc[j] = b0[orow + 16 * j];

    const float* w = W0 + (size_t)orow * K0_;
    for (int h = 0; h < F_; ++h) {
        const float xh = xs[h * D_ + d];
        const int cbase = h * F_;
#pragma unroll 1
        for (int m = 0; m < F_; ++m) {
            const float s = xh * xs[m * D_ + d];
            const int c = cbase + m;
#pragma unroll
            for (int j = 0; j < 8; ++j)
                acc[j] = fmaf(w[(size_t)j * 16 * K0_ + c], s, acc[j]);
        }
    }

#pragma unroll
    for (int j = 0; j < 8; ++j) {
        const int o = orow + 16 * j;
        const float v = fmaxf(acc[j], 0.0f);
        if (o < H1_) {
            nh[((size_t)b * H1_ + o) * D_ + d] = v;
        } else {
            ys[(o - H1_) * D_ + d] = v;
        }
    }
    __syncthreads();

    if (t < H1_) {
        float ssum = 0.0f;
#pragma unroll
        for (int i = 0; i < D_; ++i) ssum += ys[t * D_ + i];
        out[(size_t)b * OUTB_ + t] = ssum;
    }
}

// ---------------- Layer 1 ----------------
// y1[b,o,d] = relu(b1[o] + sum_{h<64,m<39} W1[o, h*39+m] * nh[b,h,d]*x[b,m,d])
// out[b, 64+o] = sum_d y1[b,o,d]
__global__ __launch_bounds__(256) void cin_layer1(
    const float* __restrict__ x, const float* __restrict__ W1,
    const float* __restrict__ b1, const float* __restrict__ nh,
    float* __restrict__ out)
{
    __shared__ float xs[F_ * D_];     // 624
    __shared__ float hs[H1_ * D_];    // 1024
    __shared__ float ys[L0_ * D_];    // 2048 floats (8 KB)

    const int b = blockIdx.x;
    const int t = threadIdx.x;
    const float* xb = x + (size_t)b * (F_ * D_);
    const float* hb = nh + (size_t)b * (H1_ * D_);
    for (int i = t; i < F_ * D_; i += 256) xs[i] = xb[i];
    for (int i = t; i < H1_ * D_; i += 256) hs[i] = hb[i];
    __syncthreads();

    const int d    = t & 15;
    const int orow = t >> 4;

    float acc[8];
#pragma unroll
    for (int j = 0; j < 8; ++j) acc[j] = b1[orow + 16 * j];

    const float* w = W1 + (size_t)orow * K1_;
    for (int h = 0; h < H1_; ++h) {
        const float xh = hs[h * D_ + d];
        const int cbase = h * F_;
#pragma unroll 1
        for (int m = 0; m < F_; ++m) {
            const float s = xh * xs[m * D_ + d];
            const int c = cbase + m;
#pragma unroll
            for (int j = 0; j < 8; ++j)
                acc[j] = fmaf(w[(size_t)j * 16 * K1_ + c], s, acc[j]);
        }
    }

#pragma unroll
    for (int j = 0; j < 8; ++j) {
        const int o = orow + 16 * j;
        ys[o * D_ + d] = fmaxf(acc[j], 0.0f);
    }
    __syncthreads();

    if (t < L0_) {
        float ssum = 0.0f;
#pragma unroll
        for (int i = 0; i < D_; ++i) ssum += ys[t * D_ + i];
        out[(size_t)b * OUTB_ + H1_ + t] = ssum;
    }
}

extern "C" void kernel_launch(void* const* d_in, const int* in_sizes, int n_in,
                              void* d_out, int out_size, void* d_ws, size_t ws_size,
                              hipStream_t stream) {
    const float* x  = (const float*)d_in[0];
    const float* W0 = (const float*)d_in[1];
    const float* b0 = (const float*)d_in[2];
    const float* W1 = (const float*)d_in[3];
    const float* b1 = (const float*)d_in[4];
    float* out = (float*)d_out;
    float* nh  = (float*)d_ws;   // B * H1 * D floats = 16 MB

    cin_layer0<<<B_, 256, 0, stream>>>(x, W0, b0, out, nh);
    cin_layer1<<<B_, 256, 0, stream>>>(x, W1, b1, nh, out);
}

// Round 2
// 85.976 us; speedup vs baseline: 98.0785x; 98.0785x over previous
//
#include <hip/hip_runtime.h>
#include <hip/hip_fp16.h>

// ---- problem constants ----
#define B_    4096
#define F_    39
#define D_    16
#define L0_   128
#define H1_   64
// K' re-order: k' = (h*5 + a)*8 + j ; m = 8a + j ; layer0 h<40(pad), layer1 h<64
#define NKK0  50          // layer0 k-chunks of 32  (40*5*8/32)
#define NKK1  80          // layer1 k-chunks of 32  (64*5*8/32)
#define NKK   (NKK0+NKK1) // 130
#define WP_ELEMS (NKK*8*64*8)  // 532480 fp16 = 1.04 MB

typedef _Float16 f16x8 __attribute__((ext_vector_type(8)));
typedef float    f32x4 __attribute__((ext_vector_type(4)));

union Frag {
    f16x8   h8;
    __half2 h2[4];
    f32x4   f4v;
};

__device__ __forceinline__ void gload_lds16(const void* g, void* l) {
    __builtin_amdgcn_global_load_lds(
        (const __attribute__((address_space(1))) void*)g,
        (__attribute__((address_space(3))) void*)l, 16, 0, 0);
}

// ---------- W pre-pack: Wp[kk][tile][lane][j] fp16, MFMA A-fragment order ----------
__global__ __launch_bounds__(256) void prep_w(
    const float* __restrict__ W0, const float* __restrict__ W1,
    __half* __restrict__ Wp)
{
    int idx = blockIdx.x * 256 + threadIdx.x;
    if (idx >= WP_ELEMS) return;
    int j    = idx & 7;
    int l    = (idx >> 3) & 63;
    int tile = (idx >> 9) & 7;
    int kk   = idx >> 12;
    int lg = l >> 4;
    int o  = tile * 16 + (l & 15);
    float v = 0.f;
    if (kk < NKK0) {
        int u = kk * 4 + lg;           // < 200
        int h = u / 5, a = u - 5 * (u / 5);
        int m = a * 8 + j;
        if (h < F_ && m < F_) v = W0[o * (F_ * F_) + h * F_ + m];
    } else {
        int u = (kk - NKK0) * 4 + lg;  // < 320
        int h = u / 5, a = u - 5 * (u / 5);
        int m = a * 8 + j;
        if (m < F_) v = W1[o * (H1_ * F_) + h * F_ + m];
    }
    Wp[idx] = __float2half(v);
}

// ---------- fused main kernel: 512 blocks x 256 thr (4 waves), 2 batches/wave ----------
__global__ __launch_bounds__(256, 2) void cin_main(
    const float* __restrict__ x, const float* __restrict__ b0,
    const float* __restrict__ b1, const __half* __restrict__ Wp,
    float* __restrict__ out)
{
    __shared__ __align__(16) __half Wl[2][2][8][64][8]; // 32 KB: dbuf x 2kk x 8 tiles
    __shared__ __align__(16) __half xT [8][16][40];     // 10 KB: [bt][d][f]  (f=39 zero pad)
    __shared__ __align__(16) __half nhT[8][16][68];     // 17 KB: [bt][d][h]

    const int t    = threadIdx.x;
    const int w    = t >> 6;
    const int lane = t & 63;
    const int d    = lane & 15;
    const int lg   = lane >> 4;
    const int gbase = blockIdx.x * 8 + w * 2;

    // ---- stage xT (wave-private, transposed, fp16) ----
#pragma unroll
    for (int bt = 0; bt < 2; ++bt) {
        const float* xb = x + (size_t)(gbase + bt) * (F_ * D_);
        const int wbt = w * 2 + bt;
        for (int i = lane; i < 640; i += 64) {
            float xv = (i < F_ * D_) ? xb[i] : 0.f;
            xT[wbt][i & 15][i >> 4] = __float2half(xv);
        }
    }

    // ---- acc init = bias b0 ----
    f32x4 acc[8][2];
#pragma unroll
    for (int tt = 0; tt < 8; ++tt) {
        f32x4 bb = *(const f32x4*)&b0[tt * 16 + lg * 4];
        acc[tt][0] = bb; acc[tt][1] = bb;
    }

    // ---- W stage helper: one round = 2 kk = 16 KB ----
    auto stage = [&](int r, int buf) {
        const __half* src = Wp + (size_t)r * 8192;
#pragma unroll
        for (int it = 0; it < 4; ++it) {
            gload_lds16(src + it * 2048 + t * 8,
                        &Wl[buf][0][0][0][0] + it * 2048 + t * 8);
        }
    };

    int buf = 0;
    stage(0, 0);
    asm volatile("s_waitcnt vmcnt(0)" ::: "memory");
    __syncthreads();

    for (int r = 0; r < NKK / 2; ++r) {
        if (r < NKK / 2 - 1) stage(r + 1, buf ^ 1);

#pragma unroll
        for (int kk2 = 0; kk2 < 2; ++kk2) {
            const int kk = 2 * r + kk2;

            if (kk == NKK0) {
                // ---- layer-0 epilogue: nh -> LDS, direct0 -> out ----
#pragma unroll
                for (int tt = 0; tt < 8; ++tt) {
#pragma unroll
                    for (int bt = 0; bt < 2; ++bt) {
                        float v0 = fmaxf(acc[tt][bt][0], 0.f);
                        float v1 = fmaxf(acc[tt][bt][1], 0.f);
                        float v2 = fmaxf(acc[tt][bt][2], 0.f);
                        float v3 = fmaxf(acc[tt][bt][3], 0.f);
                        const int wbt = w * 2 + bt;
                        if (tt < 4) {                       // rows 0..63 -> next_hidden
                            const int o = tt * 16 + lg * 4;
                            *(__half2*)&nhT[wbt][d][o]     = __floats2half2_rn(v0, v1);
                            *(__half2*)&nhT[wbt][d][o + 2] = __floats2half2_rn(v2, v3);
                        } else {                            // rows 64..127 -> direct0
#pragma unroll
                            for (int msk = 1; msk <= 8; msk <<= 1) {
                                v0 += __shfl_xor(v0, msk, 64);
                                v1 += __shfl_xor(v1, msk, 64);
                                v2 += __shfl_xor(v2, msk, 64);
                                v3 += __shfl_xor(v3, msk, 64);
                            }
                            if (d == 0) {
                                float4 s; s.x = v0; s.y = v1; s.z = v2; s.w = v3;
                                *(float4*)&out[(size_t)(gbase + bt) * 192 +
                                               tt * 16 + lg * 4 - 64] = s;
                            }
                        }
                    }
                }
#pragma unroll
                for (int tt = 0; tt < 8; ++tt) {            // re-init acc = b1
                    f32x4 bb = *(const f32x4*)&b1[tt * 16 + lg * 4];
                    acc[tt][0] = bb; acc[tt][1] = bb;
                }
            }

            // ---- B-fragments (2 batches) ----
            const int  kl = (kk < NKK0) ? kk : kk - NKK0;
            const int  u  = kl * 4 + lg;
            const int  h  = (u * 52429) >> 18;   // u/5, exact for u < 52429
            const int  a  = u - 5 * h;
            const bool L0 = (kk < NKK0);

            Frag bfr[2];
#pragma unroll
            for (int bt = 0; bt < 2; ++bt) {
                const int wbt = w * 2 + bt;
                const __half* xhrow = L0 ? &xT[wbt][d][0] : &nhT[wbt][d][0];
                __half2 xh2 = __half2half2(xhrow[h]);
                Frag xm;
                xm.f4v = *(const f32x4*)&xT[wbt][d][a * 8];
#pragma unroll
                for (int q = 0; q < 4; ++q)
                    bfr[bt].h2[q] = __hmul2(xm.h2[q], xh2);
            }

            // ---- 8 row-tiles x 2 batches MFMA ----
#pragma unroll
            for (int tt = 0; tt < 8; ++tt) {
                Frag af;
                af.f4v = *(const f32x4*)&Wl[buf][kk2][tt][lane][0];
#pragma unroll
                for (int bt = 0; bt < 2; ++bt)
                    acc[tt][bt] = __builtin_amdgcn_mfma_f32_16x16x32_f16(
                        af.h8, bfr[bt].h8, acc[tt][bt], 0, 0, 0);
            }
        }
        asm volatile("s_waitcnt vmcnt(0)" ::: "memory");
        __syncthreads();
        buf ^= 1;
    }

    // ---- layer-1 epilogue: direct1 -> out ----
#pragma unroll
    for (int tt = 0; tt < 8; ++tt) {
#pragma unroll
        for (int bt = 0; bt < 2; ++bt) {
            float v0 = fmaxf(acc[tt][bt][0], 0.f);
            float v1 = fmaxf(acc[tt][bt][1], 0.f);
            float v2 = fmaxf(acc[tt][bt][2], 0.f);
            float v3 = fmaxf(acc[tt][bt][3], 0.f);
#pragma unroll
            for (int msk = 1; msk <= 8; msk <<= 1) {
                v0 += __shfl_xor(v0, msk, 64);
                v1 += __shfl_xor(v1, msk, 64);
                v2 += __shfl_xor(v2, msk, 64);
                v3 += __shfl_xor(v3, msk, 64);
            }
            if (d == 0) {
                float4 s; s.x = v0; s.y = v1; s.z = v2; s.w = v3;
                *(float4*)&out[(size_t)(gbase + bt) * 192 + 64 + tt * 16 + lg * 4] = s;
            }
        }
    }
}

extern "C" void kernel_launch(void* const* d_in, const int* in_sizes, int n_in,
                              void* d_out, int out_size, void* d_ws, size_t ws_size,
                              hipStream_t stream) {
    const float* x  = (const float*)d_in[0];
    const float* W0 = (const float*)d_in[1];
    const float* b0 = (const float*)d_in[2];
    const float* W1 = (const float*)d_in[3];
    const float* b1 = (const float*)d_in[4];
    float* out = (float*)d_out;
    __half* Wp = (__half*)d_ws;   // 1.04 MB packed fragment-order weights

    prep_w<<<(WP_ELEMS + 255) / 256, 256, 0, stream>>>(W0, W1, Wp);
    cin_main<<<B_ / 8, 256, 0, stream>>>(x, b0, b1, Wp, out);
}